// Round 1
// baseline (97.415 us; speedup 1.0000x reference)
//
#include <hip/hip_runtime.h>

#define BB 32
#define SS 512
#define FF 256
#define NN 8

__global__ __launch_bounds__(64) void hippo_scan_naive(
    const float* __restrict__ x,
    const float* __restrict__ Ad,
    const float* __restrict__ Bd,
    float* __restrict__ out)
{
    const int tid = blockIdx.x * blockDim.x + threadIdx.x;   // 0..8191
    const int b = tid >> 8;        // / FF
    const int f = tid & (FF - 1);  // % FF

    // A (8x8) and B (8) are uniform across threads -> scalar loads expected.
    float A[NN][NN];
#pragma unroll
    for (int n = 0; n < NN; ++n)
#pragma unroll
        for (int m = 0; m < NN; ++m)
            A[n][m] = Ad[n * NN + m];

    float Bv[NN];
#pragma unroll
    for (int m = 0; m < NN; ++m) Bv[m] = Bd[m];

    float c[NN];
#pragma unroll
    for (int m = 0; m < NN; ++m) c[m] = 0.0f;

    const float* xp = x + b * (SS * FF) + f;          // stride FF per step (coalesced)
    float* op = out + (size_t)b * (SS * FF * NN) + (size_t)f * NN;

    // software pipeline: prefetch next x (only ~1 wave/SIMD, no TLP to hide latency)
    float xt = xp[0];
    for (int t = 0; t < SS; ++t) {
        float xn = 0.0f;
        if (t + 1 < SS) xn = xp[(t + 1) * FF];

        float cn[NN];
#pragma unroll
        for (int m = 0; m < NN; ++m) {
            float acc = Bv[m] * xt;
#pragma unroll
            for (int n = 0; n < NN; ++n)
                acc = fmaf(c[n], A[n][m], acc);
            cn[m] = acc;
        }
#pragma unroll
        for (int m = 0; m < NN; ++m) c[m] = cn[m];

        float4* o4 = (float4*)(op + (size_t)t * (FF * NN));
        o4[0] = make_float4(c[0], c[1], c[2], c[3]);
        o4[1] = make_float4(c[4], c[5], c[6], c[7]);

        xt = xn;
    }
}

extern "C" void kernel_launch(void* const* d_in, const int* in_sizes, int n_in,
                              void* d_out, int out_size, void* d_ws, size_t ws_size,
                              hipStream_t stream) {
    const float* x  = (const float*)d_in[0];
    const float* Ad = (const float*)d_in[1];
    const float* Bd = (const float*)d_in[2];
    float* out = (float*)d_out;

    const int threads = BB * FF;          // 8192 channels
    const int block = 64;
    const int grid = threads / block;     // 128 blocks, 1 wave each
    hipLaunchKernelGGL(hippo_scan_naive, dim3(grid), dim3(block), 0, stream,
                       x, Ad, Bd, out);
}

// Round 2
// 47.392 us; speedup vs baseline: 2.0555x; 2.0555x over previous
//
#include <hip/hip_runtime.h>

#define BB 32
#define SS 512
#define FF 256
#define NN 8

#define KC 64                 // time chunks
#define LC 8                  // steps per chunk = SS/KC
#define CG 8                  // channels per block
#define NT (KC * CG)          // 512 threads
#define XPAD 9                // x_lds row stride in words (breaks bank aliasing)
#define VSTR 68               // v_lds per-chunk stride in words

__global__ __launch_bounds__(NT, 4) void hippo_chunked(
    const float* __restrict__ x,
    const float* __restrict__ Ad,
    const float* __restrict__ Bd,
    float* __restrict__ out)
{
    __shared__ float xs[SS * XPAD];     // 18432 B
    __shared__ float vs[KC * VSTR];     // 17408 B
    __shared__ float pw[6][64];         // M^(8*2^k), k=0..5
    __shared__ float tmpm[2][64];       // matmul scratch

    const int tid = threadIdx.x;
    const int j   = tid >> 3;           // chunk id 0..63
    const int chl = tid & 7;            // channel-in-block 0..7
    const int g   = blockIdx.x;
    const int b   = g >> 5;             // 32 groups per batch (FF/CG)
    const int f0  = (g & 31) * CG;

    // Thread-uniform A (row-major [n][m]) and B -> scalar registers.
    float As[NN * NN];
#pragma unroll
    for (int i = 0; i < NN * NN; ++i) As[i] = Ad[i];
    float Bv[NN];
#pragma unroll
    for (int m = 0; m < NN; ++m) Bv[m] = Bd[m];

    // ---- stage x for this block's 8 channels into LDS (padded) ----
    {
        const float* xb = x + (size_t)b * SS * FF + f0;
#pragma unroll
        for (int it = 0; it < 2; ++it) {
            int i = tid + it * NT;          // float4 index 0..1023
            int t = i >> 1, q = i & 1;
            float4 vx = *(const float4*)(xb + t * FF + q * 4);
            float* dst = &xs[t * XPAD + q * 4];
            dst[0] = vx.x; dst[1] = vx.y; dst[2] = vx.z; dst[3] = vx.w;
        }
    }

    // ---- wave 0: matrix powers pw[k] = M^(8*2^k), M[m][n] = A[n][m] ----
    if (tid < 64) {
        const int m = tid >> 3, n = tid & 7;
        tmpm[0][tid] = Ad[n * NN + m];                 // M^1
        // M^2 -> tmpm[1], M^4 -> tmpm[0], M^8 -> pw[0], then square up to pw[5]
        {
            float a = 0.f;
#pragma unroll
            for (int t = 0; t < 8; ++t) a = fmaf(tmpm[0][m*8+t], tmpm[0][t*8+n], a);
            tmpm[1][tid] = a;
        }
        {
            float a = 0.f;
#pragma unroll
            for (int t = 0; t < 8; ++t) a = fmaf(tmpm[1][m*8+t], tmpm[1][t*8+n], a);
            tmpm[0][tid] = a;
        }
        {
            float a = 0.f;
#pragma unroll
            for (int t = 0; t < 8; ++t) a = fmaf(tmpm[0][m*8+t], tmpm[0][t*8+n], a);
            pw[0][tid] = a;
        }
#pragma unroll
        for (int k = 1; k < 6; ++k) {
            float a = 0.f;
#pragma unroll
            for (int t = 0; t < 8; ++t) a = fmaf(pw[k-1][m*8+t], pw[k-1][t*8+n], a);
            pw[k][tid] = a;
        }
    }
    __syncthreads();

    // ---- phase 1: local scan of chunk j from zero state ----
    const int t0 = j * LC;
    float c[NN];
#pragma unroll
    for (int m = 0; m < NN; ++m) c[m] = 0.f;
#pragma unroll
    for (int t = 0; t < LC; ++t) {
        float xt = xs[(t0 + t) * XPAD + chl];
        float cn[NN];
#pragma unroll
        for (int m = 0; m < NN; ++m) {
            float a = Bv[m] * xt;
#pragma unroll
            for (int n = 0; n < NN; ++n) a = fmaf(As[n * NN + m], c[n], a);
            cn[m] = a;
        }
#pragma unroll
        for (int m = 0; m < NN; ++m) c[m] = cn[m];
    }
    {
        float* vj = &vs[j * VSTR + chl * NN];
#pragma unroll
        for (int m = 0; m < NN; ++m) vj[m] = c[m];
    }
    __syncthreads();

    // ---- phase 2: Hillis-Steele scan over chunk states (6 levels) ----
    float s[NN];
#pragma unroll
    for (int m = 0; m < NN; ++m) s[m] = c[m];
#pragma unroll
    for (int k = 0; k < 6; ++k) {
        const int d = 1 << k;
        float prev[NN];
        if (j >= d) {
            const float* vp = &vs[(j - d) * VSTR + chl * NN];
#pragma unroll
            for (int m = 0; m < NN; ++m) prev[m] = vp[m];
        }
        __syncthreads();
        if (j >= d) {
#pragma unroll
            for (int m = 0; m < NN; ++m) {
                float a = s[m];
#pragma unroll
                for (int n = 0; n < NN; ++n) a = fmaf(pw[k][m * 8 + n], prev[n], a);
                s[m] = a;
            }
            float* vj = &vs[j * VSTR + chl * NN];
#pragma unroll
            for (int m = 0; m < NN; ++m) vj[m] = s[m];
        }
        __syncthreads();
    }

    // ---- phase 3: re-scan chunk j from true incoming state, store ----
    float ci[NN];
    if (j > 0) {
        const float* vp = &vs[(j - 1) * VSTR + chl * NN];
#pragma unroll
        for (int m = 0; m < NN; ++m) ci[m] = vp[m];
    } else {
#pragma unroll
        for (int m = 0; m < NN; ++m) ci[m] = 0.f;
    }

    float* op = out + ((size_t)b * SS + t0) * (FF * NN) + (size_t)(f0 + chl) * NN;
#pragma unroll
    for (int t = 0; t < LC; ++t) {
        float xt = xs[(t0 + t) * XPAD + chl];
        float cn[NN];
#pragma unroll
        for (int m = 0; m < NN; ++m) {
            float a = Bv[m] * xt;
#pragma unroll
            for (int n = 0; n < NN; ++n) a = fmaf(As[n * NN + m], ci[n], a);
            cn[m] = a;
        }
#pragma unroll
        for (int m = 0; m < NN; ++m) ci[m] = cn[m];

        float4* o4 = (float4*)(op + (size_t)t * (FF * NN));
        o4[0] = make_float4(ci[0], ci[1], ci[2], ci[3]);
        o4[1] = make_float4(ci[4], ci[5], ci[6], ci[7]);
    }
}

extern "C" void kernel_launch(void* const* d_in, const int* in_sizes, int n_in,
                              void* d_out, int out_size, void* d_ws, size_t ws_size,
                              hipStream_t stream) {
    const float* x  = (const float*)d_in[0];
    const float* Ad = (const float*)d_in[1];
    const float* Bd = (const float*)d_in[2];
    float* out = (float*)d_out;

    const int grid = (BB * FF) / CG;   // 1024 blocks
    hipLaunchKernelGGL(hippo_chunked, dim3(grid), dim3(NT), 0, stream,
                       x, Ad, Bd, out);
}

// Round 3
// 46.901 us; speedup vs baseline: 2.0770x; 1.0105x over previous
//
#include <hip/hip_runtime.h>

#define BB 32
#define SS 512
#define FF 256
#define NN 8

#define L2C 16              // chunk length
#define NCH (SS / L2C)      // 32 chunks
#define CG1 16              // channels per block (kernel 1)
#define NT1 (NCH * CG1)     // 512 threads (kernel 1)
#define VSTR 136            // vs row stride (words), 16B-aligned rows

// ---------------- kernel 1: chunk-incoming states -> ws ----------------
// ws[b][j][f][n] = state entering chunk j of channel (b,f); ws[b][0][f][:]=0.
__global__ __launch_bounds__(NT1) void hippo_states(
    const float* __restrict__ x,
    const float* __restrict__ Ad,
    const float* __restrict__ Bd,
    float* __restrict__ ws)
{
    __shared__ float vs[NCH * VSTR];    // 17408 B
    __shared__ float pw[5][64];         // M^(16*2^k), k=0..4
    __shared__ float tmpm[2][64];

    const int tid = threadIdx.x;
    const int j   = tid >> 4;           // chunk 0..31
    const int chl = tid & 15;           // channel-in-block
    const int b   = blockIdx.x >> 4;    // FF/CG1 = 16 groups per batch
    const int f0  = (blockIdx.x & 15) * CG1;

    // thread-uniform A (row-major [n][m]) and B -> scalar regs
    float As[NN * NN];
#pragma unroll
    for (int i = 0; i < NN * NN; ++i) As[i] = Ad[i];
    float Bv[NN];
#pragma unroll
    for (int m = 0; m < NN; ++m) Bv[m] = Bd[m];

    // wave 0: matrix powers. M[m][n] = A[n][m]; pw[k] = M^(16*2^k)
    if (tid < 64) {
        const int m = tid >> 3, n = tid & 7;
        tmpm[0][tid] = Ad[n * NN + m];                    // M^1
        {   float a = 0.f;                                // M^2
#pragma unroll
            for (int t = 0; t < 8; ++t) a = fmaf(tmpm[0][m*8+t], tmpm[0][t*8+n], a);
            tmpm[1][tid] = a; }
        {   float a = 0.f;                                // M^4
#pragma unroll
            for (int t = 0; t < 8; ++t) a = fmaf(tmpm[1][m*8+t], tmpm[1][t*8+n], a);
            tmpm[0][tid] = a; }
        {   float a = 0.f;                                // M^8
#pragma unroll
            for (int t = 0; t < 8; ++t) a = fmaf(tmpm[0][m*8+t], tmpm[0][t*8+n], a);
            tmpm[1][tid] = a; }
        {   float a = 0.f;                                // M^16
#pragma unroll
            for (int t = 0; t < 8; ++t) a = fmaf(tmpm[1][m*8+t], tmpm[1][t*8+n], a);
            pw[0][tid] = a; }
#pragma unroll
        for (int k = 1; k < 5; ++k) {
            float a = 0.f;
#pragma unroll
            for (int t = 0; t < 8; ++t) a = fmaf(pw[k-1][m*8+t], pw[k-1][t*8+n], a);
            pw[k][tid] = a;
        }
    }
    __syncthreads();

    // local scan of chunk j from zero state (x read direct from global: dense 64B rows)
    const int t0 = j * L2C;
    const float* xp = x + ((size_t)b * SS + t0) * FF + f0 + chl;
    float c[NN];
#pragma unroll
    for (int m = 0; m < NN; ++m) c[m] = 0.f;
#pragma unroll
    for (int t = 0; t < L2C; ++t) {
        float xt = xp[(size_t)t * FF];
        float cn[NN];
#pragma unroll
        for (int m = 0; m < NN; ++m) {
            float a = Bv[m] * xt;
#pragma unroll
            for (int n = 0; n < NN; ++n) a = fmaf(As[n * NN + m], c[n], a);
            cn[m] = a;
        }
#pragma unroll
        for (int m = 0; m < NN; ++m) c[m] = cn[m];
    }
    {
        float* vj = &vs[j * VSTR + chl * NN];
#pragma unroll
        for (int m = 0; m < NN; ++m) vj[m] = c[m];
    }
    __syncthreads();

    // Hillis-Steele inclusive scan over 32 chunk states (5 levels)
    float s[NN];
#pragma unroll
    for (int m = 0; m < NN; ++m) s[m] = c[m];
#pragma unroll
    for (int k = 0; k < 5; ++k) {
        const int d = 1 << k;
        float prev[NN];
        if (j >= d) {
            const float* vp = &vs[(j - d) * VSTR + chl * NN];
#pragma unroll
            for (int m = 0; m < NN; ++m) prev[m] = vp[m];
        }
        __syncthreads();
        if (j >= d) {
#pragma unroll
            for (int m = 0; m < NN; ++m) {
                float a = s[m];
#pragma unroll
                for (int n = 0; n < NN; ++n) a = fmaf(pw[k][m * 8 + n], prev[n], a);
                s[m] = a;
            }
            float* vj = &vs[j * VSTR + chl * NN];
#pragma unroll
            for (int m = 0; m < NN; ++m) vj[m] = s[m];
        }
        __syncthreads();
    }

    // incoming state for chunk j+1 = inclusive state of chunk j
    const int f = f0 + chl;
    if (j < NCH - 1) {
        float* wp = ws + (((size_t)b * NCH + (j + 1)) * FF + f) * NN;
        float4* w4 = (float4*)wp;
        w4[0] = make_float4(s[0], s[1], s[2], s[3]);
        w4[1] = make_float4(s[4], s[5], s[6], s[7]);
    } else {
        float* wp = ws + (((size_t)b * NCH + 0) * FF + f) * NN;
        float4* w4 = (float4*)wp;
        w4[0] = make_float4(0.f, 0.f, 0.f, 0.f);
        w4[1] = make_float4(0.f, 0.f, 0.f, 0.f);
    }
}

// ---------------- kernel 2: emit outputs (no barriers, no LDS) ----------------
__global__ __launch_bounds__(FF) void hippo_emit(
    const float* __restrict__ x,
    const float* __restrict__ Ad,
    const float* __restrict__ Bd,
    const float* __restrict__ ws,
    float* __restrict__ out)
{
    const int f  = threadIdx.x;          // channel 0..255
    const int j  = blockIdx.x & (NCH - 1);
    const int b  = blockIdx.x >> 5;      // NCH = 32
    const int t0 = j * L2C;

    float As[NN * NN];
#pragma unroll
    for (int i = 0; i < NN * NN; ++i) As[i] = Ad[i];
    float Bv[NN];
#pragma unroll
    for (int m = 0; m < NN; ++m) Bv[m] = Bd[m];

    // incoming state
    float c[NN];
    {
        const float* wp = ws + (((size_t)b * NCH + j) * FF + f) * NN;
        const float4* w4 = (const float4*)wp;
        float4 a0 = w4[0], a1 = w4[1];
        c[0] = a0.x; c[1] = a0.y; c[2] = a0.z; c[3] = a0.w;
        c[4] = a1.x; c[5] = a1.y; c[6] = a1.z; c[7] = a1.w;
    }

    const float* xp = x + ((size_t)b * SS + t0) * FF + f;            // +FF per step (coalesced)
    float* op = out + ((size_t)b * SS + t0) * (FF * NN) + (size_t)f * NN;

#pragma unroll
    for (int t = 0; t < L2C; ++t) {
        float xt = xp[(size_t)t * FF];
        float cn[NN];
#pragma unroll
        for (int m = 0; m < NN; ++m) {
            float a = Bv[m] * xt;
#pragma unroll
            for (int n = 0; n < NN; ++n) a = fmaf(As[n * NN + m], c[n], a);
            cn[m] = a;
        }
#pragma unroll
        for (int m = 0; m < NN; ++m) c[m] = cn[m];

        float4* o4 = (float4*)(op + (size_t)t * (FF * NN));
        o4[0] = make_float4(c[0], c[1], c[2], c[3]);
        o4[1] = make_float4(c[4], c[5], c[6], c[7]);
    }
}

extern "C" void kernel_launch(void* const* d_in, const int* in_sizes, int n_in,
                              void* d_out, int out_size, void* d_ws, size_t ws_size,
                              hipStream_t stream) {
    const float* x  = (const float*)d_in[0];
    const float* Ad = (const float*)d_in[1];
    const float* Bd = (const float*)d_in[2];
    float* out = (float*)d_out;
    float* ws  = (float*)d_ws;   // needs BB*NCH*FF*NN*4 = 8 MiB

    const int grid1 = BB * (FF / CG1);   // 512 blocks x 512 threads
    hipLaunchKernelGGL(hippo_states, dim3(grid1), dim3(NT1), 0, stream,
                       x, Ad, Bd, ws);

    const int grid2 = BB * NCH;          // 1024 blocks x 256 threads
    hipLaunchKernelGGL(hippo_emit, dim3(grid2), dim3(FF), 0, stream,
                       x, Ad, Bd, ws, out);
}

// Round 4
// 46.197 us; speedup vs baseline: 2.1087x; 1.0152x over previous
//
#include <hip/hip_runtime.h>

#define BB 32
#define SS 512
#define FF 256
#define NN 8

#define L2C 16              // chunk length
#define NCH (SS / L2C)      // 32 chunks
#define CG1 16              // channels per block (kernel 1)
#define NT1 (NCH * CG1)     // 512 threads (kernel 1)
#define VSTR 136            // vs row stride (words)

// ---------------- kernel 1: chunk-incoming states -> ws ----------------
// ws[b][j][f][n] = state entering chunk j of channel (b,f); ws[b][0][f][:]=0.
__global__ __launch_bounds__(NT1) void hippo_states(
    const float* __restrict__ x,
    const float* __restrict__ Ad,
    const float* __restrict__ Bd,
    float* __restrict__ ws)
{
    __shared__ float vs[NCH * VSTR];
    __shared__ float pw[5][64];         // M^(16*2^k), k=0..4
    __shared__ float tmpm[2][64];

    const int tid = threadIdx.x;
    const int j   = tid >> 4;
    const int chl = tid & 15;
    const int b   = blockIdx.x >> 4;
    const int f0  = (blockIdx.x & 15) * CG1;

    float As[NN * NN];
#pragma unroll
    for (int i = 0; i < NN * NN; ++i) As[i] = Ad[i];
    float Bv[NN];
#pragma unroll
    for (int m = 0; m < NN; ++m) Bv[m] = Bd[m];

    if (tid < 64) {
        const int m = tid >> 3, n = tid & 7;
        tmpm[0][tid] = Ad[n * NN + m];                    // M^1
        {   float a = 0.f;
#pragma unroll
            for (int t = 0; t < 8; ++t) a = fmaf(tmpm[0][m*8+t], tmpm[0][t*8+n], a);
            tmpm[1][tid] = a; }                           // M^2
        {   float a = 0.f;
#pragma unroll
            for (int t = 0; t < 8; ++t) a = fmaf(tmpm[1][m*8+t], tmpm[1][t*8+n], a);
            tmpm[0][tid] = a; }                           // M^4
        {   float a = 0.f;
#pragma unroll
            for (int t = 0; t < 8; ++t) a = fmaf(tmpm[0][m*8+t], tmpm[0][t*8+n], a);
            tmpm[1][tid] = a; }                           // M^8
        {   float a = 0.f;
#pragma unroll
            for (int t = 0; t < 8; ++t) a = fmaf(tmpm[1][m*8+t], tmpm[1][t*8+n], a);
            pw[0][tid] = a; }                             // M^16
#pragma unroll
        for (int k = 1; k < 5; ++k) {
            float a = 0.f;
#pragma unroll
            for (int t = 0; t < 8; ++t) a = fmaf(pw[k-1][m*8+t], pw[k-1][t*8+n], a);
            pw[k][tid] = a;
        }
    }
    __syncthreads();

    const int t0 = j * L2C;
    const float* xp = x + ((size_t)b * SS + t0) * FF + f0 + chl;
    float c[NN];
#pragma unroll
    for (int m = 0; m < NN; ++m) c[m] = 0.f;
#pragma unroll
    for (int t = 0; t < L2C; ++t) {
        float xt = xp[(size_t)t * FF];
        float cn[NN];
#pragma unroll
        for (int m = 0; m < NN; ++m) {
            float a = Bv[m] * xt;
#pragma unroll
            for (int n = 0; n < NN; ++n) a = fmaf(As[n * NN + m], c[n], a);
            cn[m] = a;
        }
#pragma unroll
        for (int m = 0; m < NN; ++m) c[m] = cn[m];
    }
    {
        float* vj = &vs[j * VSTR + chl * NN];
#pragma unroll
        for (int m = 0; m < NN; ++m) vj[m] = c[m];
    }
    __syncthreads();

    float s[NN];
#pragma unroll
    for (int m = 0; m < NN; ++m) s[m] = c[m];
#pragma unroll
    for (int k = 0; k < 5; ++k) {
        const int d = 1 << k;
        float prev[NN];
        if (j >= d) {
            const float* vp = &vs[(j - d) * VSTR + chl * NN];
#pragma unroll
            for (int m = 0; m < NN; ++m) prev[m] = vp[m];
        }
        __syncthreads();
        if (j >= d) {
#pragma unroll
            for (int m = 0; m < NN; ++m) {
                float a = s[m];
#pragma unroll
                for (int n = 0; n < NN; ++n) a = fmaf(pw[k][m * 8 + n], prev[n], a);
                s[m] = a;
            }
            float* vj = &vs[j * VSTR + chl * NN];
#pragma unroll
            for (int m = 0; m < NN; ++m) vj[m] = s[m];
        }
        __syncthreads();
    }

    const int f = f0 + chl;
    if (j < NCH - 1) {
        float4* w4 = (float4*)(ws + (((size_t)b * NCH + (j + 1)) * FF + f) * NN);
        w4[0] = make_float4(s[0], s[1], s[2], s[3]);
        w4[1] = make_float4(s[4], s[5], s[6], s[7]);
    } else {
        float4* w4 = (float4*)(ws + (((size_t)b * NCH + 0) * FF + f) * NN);
        w4[0] = make_float4(0.f, 0.f, 0.f, 0.f);
        w4[1] = make_float4(0.f, 0.f, 0.f, 0.f);
    }
}

// ---------------- kernel 2: emit, 2 threads per channel, DENSE stores ----------------
// thread parity p owns state half c[4p..4p+3]; per step computes its 4 outputs,
// stores one float4 at tid*16B (lane-dense), exchanges new halves via shfl_xor(1).
__global__ __launch_bounds__(256) void hippo_emit2(
    const float* __restrict__ x,
    const float* __restrict__ Ad,
    const float* __restrict__ Bd,
    const float* __restrict__ ws,
    float* __restrict__ out)
{
    const int tid = threadIdx.x;          // 0..255 -> 128 channels
    const int p   = tid & 1;
    const int bid = blockIdx.x;
    const int b   = bid >> 6;             // 64 blocks per batch (NCH*2)
    const int rem = bid & 63;
    const int j   = rem >> 1;
    const int h   = rem & 1;
    const int f0  = h * 128;
    const int t0  = j * L2C;
    const int ch  = f0 + (tid >> 1);

    // per-parity effective A block (8x4) and B half, from L1/L2-cached Ad/Bd.
    // c_reg layout: r=0..3 own half (indices p*4+r), r=4..7 other half ((1-p)*4+(r-4)).
    // output m = p*4+m'.  Aeff[r][m'] = Ad[n(r)*8 + p*4 + m'],  n(r) = (r + p*4) & 7.
    float4 Ar[8];
#pragma unroll
    for (int r = 0; r < 8; ++r) {
        const int n = (r + p * 4) & 7;
        Ar[r] = *(const float4*)(Ad + n * NN + p * 4);
    }
    const float4 Bv4 = *(const float4*)(Bd + p * 4);

    // incoming state: own half is a dense float4 at ws_base + tid*16B
    float c[8];
    {
        const float4* w4 = (const float4*)(ws + (((size_t)b * NCH + j) * FF + f0) * NN) + tid;
        float4 own = *w4;
        c[0] = own.x; c[1] = own.y; c[2] = own.z; c[3] = own.w;
#pragma unroll
        for (int q = 0; q < 4; ++q) c[4 + q] = __shfl_xor(c[q], 1);
    }

    const float* xp = x + ((size_t)b * SS + t0) * FF + ch;
    float4* o4 = (float4*)(out + (((size_t)b * SS + t0) * FF + f0) * NN) + tid;

#pragma unroll
    for (int t = 0; t < L2C; ++t) {
        const float xt = xp[(size_t)t * FF];
        float cn[4];
#pragma unroll
        for (int m = 0; m < 4; ++m) {
            float a = ((const float*)&Bv4)[m] * xt;
#pragma unroll
            for (int r = 0; r < 8; ++r)
                a = fmaf(((const float*)&Ar[r])[m], c[r], a);
            cn[m] = a;
        }

        o4[(size_t)t * (FF * NN / 4)] = make_float4(cn[0], cn[1], cn[2], cn[3]);

#pragma unroll
        for (int q = 0; q < 4; ++q) {
            c[4 + q] = __shfl_xor(cn[q], 1);
            c[q] = cn[q];
        }
    }
}

extern "C" void kernel_launch(void* const* d_in, const int* in_sizes, int n_in,
                              void* d_out, int out_size, void* d_ws, size_t ws_size,
                              hipStream_t stream) {
    const float* x  = (const float*)d_in[0];
    const float* Ad = (const float*)d_in[1];
    const float* Bd = (const float*)d_in[2];
    float* out = (float*)d_out;
    float* ws  = (float*)d_ws;   // BB*NCH*FF*NN*4 = 8 MiB

    const int grid1 = BB * (FF / CG1);   // 512 blocks x 512 threads
    hipLaunchKernelGGL(hippo_states, dim3(grid1), dim3(NT1), 0, stream,
                       x, Ad, Bd, ws);

    const int grid2 = BB * NCH * 2;      // 2048 blocks x 256 threads
    hipLaunchKernelGGL(hippo_emit2, dim3(grid2), dim3(256), 0, stream,
                       x, Ad, Bd, ws, out);
}

// Round 5
// 43.367 us; speedup vs baseline: 2.2463x; 1.0653x over previous
//
#include <hip/hip_runtime.h>

#define BB 32
#define SS 512
#define FF 256
#define NN 8

#define L2C 16              // chunk length
#define NCH (SS / L2C)      // 32 chunks
#define CG1 16              // channels per block (kernel 1)
#define NT1 (NCH * CG1)     // 512 threads (kernel 1)
#define VSTR 136            // vs row stride (words)

// ---------------- kernel 1: chunk-incoming states -> ws (Krylov phase-1) ----------------
// ws[b][j][f][n] = state entering chunk j of channel (b,f); ws[b][0][f][:]=0.
__global__ __launch_bounds__(NT1) void hippo_states(
    const float* __restrict__ x,
    const float* __restrict__ Ad,
    const float* __restrict__ Bd,
    float* __restrict__ ws)
{
    __shared__ float vs[NCH * VSTR];
    __shared__ float pw[5][64];     // M^(16*2^k), k=0..4
    __shared__ float Mp[4][64];     // M^1, M^2, M^4, M^8
    __shared__ float Ks[16][8];     // K[i][n] = (M^(15-i) B)[n]

    const int tid = threadIdx.x;
    const int j   = tid >> 4;       // chunk 0..31
    const int chl = tid & 15;
    const int b   = blockIdx.x >> 4;
    const int f0  = (blockIdx.x & 15) * CG1;

    // ---- wave 0: tiny matrix algebra (M powers, scan powers, Krylov basis) ----
    if (tid < 64) {
        const int m = tid >> 3, n = tid & 7;
        Mp[0][tid] = Ad[n * NN + m];                 // M = A^T
#pragma unroll
        for (int s = 1; s < 4; ++s) {                // M^2, M^4, M^8
            float a = 0.f;
#pragma unroll
            for (int t = 0; t < 8; ++t) a = fmaf(Mp[s-1][m*8+t], Mp[s-1][t*8+n], a);
            Mp[s][tid] = a;
        }
        {   float a = 0.f;                           // M^16
#pragma unroll
            for (int t = 0; t < 8; ++t) a = fmaf(Mp[3][m*8+t], Mp[3][t*8+n], a);
            pw[0][tid] = a; }
#pragma unroll
        for (int k = 1; k < 5; ++k) {                // M^32..M^256
            float a = 0.f;
#pragma unroll
            for (int t = 0; t < 8; ++t) a = fmaf(pw[k-1][m*8+t], pw[k-1][t*8+n], a);
            pw[k][tid] = a;
        }
        // Krylov columns: lane i computes K[i] = M^(15-i) B via bit-decomposed matvecs
        if (tid < 16) {
            const int e = 15 - tid;
            float v[8];
#pragma unroll
            for (int q = 0; q < 8; ++q) v[q] = Bd[q];
#pragma unroll
            for (int s = 0; s < 4; ++s) {
                if (e & (1 << s)) {
                    float nv[8];
#pragma unroll
                    for (int r = 0; r < 8; ++r) {
                        float a = 0.f;
#pragma unroll
                        for (int c2 = 0; c2 < 8; ++c2)
                            a = fmaf(Mp[s][r * 8 + c2], v[c2], a);
                        nv[r] = a;
                    }
#pragma unroll
                    for (int r = 0; r < 8; ++r) v[r] = nv[r];
                }
            }
#pragma unroll
            for (int r = 0; r < 8; ++r) Ks[tid][r] = v[r];
        }
    }
    __syncthreads();

    // ---- phase 1: chunk-end state from zero via Krylov sum (8 FMA/step) ----
    const int t0 = j * L2C;
    const float* xp = x + ((size_t)b * SS + t0) * FF + f0 + chl;
    float c[NN];
#pragma unroll
    for (int m = 0; m < NN; ++m) c[m] = 0.f;
#pragma unroll
    for (int t = 0; t < L2C; ++t) {
        const float xt = xp[(size_t)t * FF];
#pragma unroll
        for (int m = 0; m < NN; ++m) c[m] = fmaf(Ks[t][m], xt, c[m]);
    }
    {
        float* vj = &vs[j * VSTR + chl * NN];
#pragma unroll
        for (int m = 0; m < NN; ++m) vj[m] = c[m];
    }
    __syncthreads();

    // ---- phase 2: Hillis-Steele scan over 32 chunk states ----
    float s[NN];
#pragma unroll
    for (int m = 0; m < NN; ++m) s[m] = c[m];
#pragma unroll
    for (int k = 0; k < 5; ++k) {
        const int d = 1 << k;
        float prev[NN];
        if (j >= d) {
            const float* vp = &vs[(j - d) * VSTR + chl * NN];
#pragma unroll
            for (int m = 0; m < NN; ++m) prev[m] = vp[m];
        }
        __syncthreads();
        if (j >= d) {
#pragma unroll
            for (int m = 0; m < NN; ++m) {
                float a = s[m];
#pragma unroll
                for (int n = 0; n < NN; ++n) a = fmaf(pw[k][m * 8 + n], prev[n], a);
                s[m] = a;
            }
            float* vj = &vs[j * VSTR + chl * NN];
#pragma unroll
            for (int m = 0; m < NN; ++m) vj[m] = s[m];
        }
        __syncthreads();
    }

    const int f = f0 + chl;
    if (j < NCH - 1) {
        float4* w4 = (float4*)(ws + (((size_t)b * NCH + (j + 1)) * FF + f) * NN);
        w4[0] = make_float4(s[0], s[1], s[2], s[3]);
        w4[1] = make_float4(s[4], s[5], s[6], s[7]);
    } else {
        float4* w4 = (float4*)(ws + (((size_t)b * NCH + 0) * FF + f) * NN);
        w4[0] = make_float4(0.f, 0.f, 0.f, 0.f);
        w4[1] = make_float4(0.f, 0.f, 0.f, 0.f);
    }
}

// ---------------- kernel 2: emit (UNCHANGED from round 4) ----------------
__global__ __launch_bounds__(256) void hippo_emit2(
    const float* __restrict__ x,
    const float* __restrict__ Ad,
    const float* __restrict__ Bd,
    const float* __restrict__ ws,
    float* __restrict__ out)
{
    const int tid = threadIdx.x;          // 0..255 -> 128 channels
    const int p   = tid & 1;
    const int bid = blockIdx.x;
    const int b   = bid >> 6;             // 64 blocks per batch (NCH*2)
    const int rem = bid & 63;
    const int j   = rem >> 1;
    const int h   = rem & 1;
    const int f0  = h * 128;
    const int t0  = j * L2C;
    const int ch  = f0 + (tid >> 1);

    float4 Ar[8];
#pragma unroll
    for (int r = 0; r < 8; ++r) {
        const int n = (r + p * 4) & 7;
        Ar[r] = *(const float4*)(Ad + n * NN + p * 4);
    }
    const float4 Bv4 = *(const float4*)(Bd + p * 4);

    float c[8];
    {
        const float4* w4 = (const float4*)(ws + (((size_t)b * NCH + j) * FF + f0) * NN) + tid;
        float4 own = *w4;
        c[0] = own.x; c[1] = own.y; c[2] = own.z; c[3] = own.w;
#pragma unroll
        for (int q = 0; q < 4; ++q) c[4 + q] = __shfl_xor(c[q], 1);
    }

    const float* xp = x + ((size_t)b * SS + t0) * FF + ch;
    float4* o4 = (float4*)(out + (((size_t)b * SS + t0) * FF + f0) * NN) + tid;

#pragma unroll
    for (int t = 0; t < L2C; ++t) {
        const float xt = xp[(size_t)t * FF];
        float cn[4];
#pragma unroll
        for (int m = 0; m < 4; ++m) {
            float a = ((const float*)&Bv4)[m] * xt;
#pragma unroll
            for (int r = 0; r < 8; ++r)
                a = fmaf(((const float*)&Ar[r])[m], c[r], a);
            cn[m] = a;
        }

        o4[(size_t)t * (FF * NN / 4)] = make_float4(cn[0], cn[1], cn[2], cn[3]);

#pragma unroll
        for (int q = 0; q < 4; ++q) {
            c[4 + q] = __shfl_xor(cn[q], 1);
            c[q] = cn[q];
        }
    }
}

extern "C" void kernel_launch(void* const* d_in, const int* in_sizes, int n_in,
                              void* d_out, int out_size, void* d_ws, size_t ws_size,
                              hipStream_t stream) {
    const float* x  = (const float*)d_in[0];
    const float* Ad = (const float*)d_in[1];
    const float* Bd = (const float*)d_in[2];
    float* out = (float*)d_out;
    float* ws  = (float*)d_ws;   // BB*NCH*FF*NN*4 = 8 MiB

    const int grid1 = BB * (FF / CG1);   // 512 blocks x 512 threads
    hipLaunchKernelGGL(hippo_states, dim3(grid1), dim3(NT1), 0, stream,
                       x, Ad, Bd, ws);

    const int grid2 = BB * NCH * 2;      // 2048 blocks x 256 threads
    hipLaunchKernelGGL(hippo_emit2, dim3(grid2), dim3(256), 0, stream,
                       x, Ad, Bd, ws, out);
}

// Round 7
// 37.096 us; speedup vs baseline: 2.6261x; 1.1691x over previous
//
#include <hip/hip_runtime.h>

#define BB 32
#define SS 512
#define FF 256
#define NN 8
#define L 16               // chunk length
#define NCH 32             // SS/L
#define CGF 8              // channels per block
#define NTF 256            // threads per block = NCH*CGF
#define XST 9              // xs row stride (words) — bank spread
#define VST 68             // vs row stride (words) — 16B-aligned, bank spread

__global__ __launch_bounds__(NTF) void hippo_fused(
    const float* __restrict__ x,
    const float* __restrict__ Ad,
    const float* __restrict__ Bd,
    float* __restrict__ out)
{
    __shared__ __align__(16) float xs[SS * XST];      // 18432 B
    __shared__ __align__(16) float vs[NCH * VST];     //  8704 B
    __shared__ __align__(16) float pw[5][64];         // P^(2^k), P = M^16
    __shared__ __align__(16) float Mp[4][64];         // M^1,2,4,8
    __shared__ __align__(16) float Ks[L][NN];         // K[i] = M^(15-i) B

    const int tid = threadIdx.x;
    const int j   = tid >> 3;           // chunk 0..31
    const int ch  = tid & 7;            // channel-in-block

    // XCD-chunked swizzle: each XCD owns 128 consecutive logical blocks
    const int h  = blockIdx.x;
    const int g  = (h & 7) * 128 + (h >> 3);
    const int b  = g >> 5;
    const int f0 = (g & 31) * CGF;

    // thread-uniform A (row-major [n][m]) and B -> SGPRs
    float As[NN * NN];
#pragma unroll
    for (int i = 0; i < NN * NN; ++i) As[i] = Ad[i];
    float Bv[NN];
#pragma unroll
    for (int m = 0; m < NN; ++m) Bv[m] = Bd[m];

    // ---- wave 0: matrix algebra (powers + Krylov basis) ----
    if (tid < 64) {
        const int m = tid >> 3, n = tid & 7;
        Mp[0][tid] = Ad[n * NN + m];                 // M = A^T
#pragma unroll
        for (int s = 1; s < 4; ++s) {                // M^2, M^4, M^8
            float a = 0.f;
#pragma unroll
            for (int t = 0; t < 8; ++t) a = fmaf(Mp[s-1][m*8+t], Mp[s-1][t*8+n], a);
            Mp[s][tid] = a;
        }
        {   float a = 0.f;                           // M^16
#pragma unroll
            for (int t = 0; t < 8; ++t) a = fmaf(Mp[3][m*8+t], Mp[3][t*8+n], a);
            pw[0][tid] = a; }
#pragma unroll
        for (int k = 1; k < 5; ++k) {                // M^32..M^256
            float a = 0.f;
#pragma unroll
            for (int t = 0; t < 8; ++t) a = fmaf(pw[k-1][m*8+t], pw[k-1][t*8+n], a);
            pw[k][tid] = a;
        }
        if (tid < L) {                               // K[i] = M^(15-i) B
            const int e = 15 - tid;
            float v[8];
#pragma unroll
            for (int q = 0; q < 8; ++q) v[q] = Bd[q];
#pragma unroll
            for (int s = 0; s < 4; ++s) {
                if (e & (1 << s)) {
                    float nv[8];
#pragma unroll
                    for (int r = 0; r < 8; ++r) {
                        float a = 0.f;
#pragma unroll
                        for (int c2 = 0; c2 < 8; ++c2)
                            a = fmaf(Mp[s][r * 8 + c2], v[c2], a);
                        nv[r] = a;
                    }
#pragma unroll
                    for (int r = 0; r < 8; ++r) v[r] = nv[r];
                }
            }
#pragma unroll
            for (int r = 0; r < 8; ++r) Ks[tid][r] = v[r];
        }
    }

    // ---- stage x tile (512 t x 8 ch = 1024 float4) into LDS, coalesced ----
    {
        const float* xb = x + (size_t)b * SS * FF + f0;
#pragma unroll
        for (int k = 0; k < 4; ++k) {
            const int i2 = tid + k * NTF;       // 0..1023
            const int t  = i2 >> 1, q = i2 & 1;
            float4 v = *(const float4*)(xb + (size_t)t * FF + q * 4);
            float* d = &xs[t * XST + q * 4];
            d[0] = v.x; d[1] = v.y; d[2] = v.z; d[3] = v.w;
        }
    }
    __syncthreads();

    // ---- phase 1: chunk-end state from zero via Krylov sum ----
    const int t0 = j * L;
    float c[NN];
#pragma unroll
    for (int m = 0; m < NN; ++m) c[m] = 0.f;
#pragma unroll
    for (int i = 0; i < L; ++i) {
        const float xt = xs[(t0 + i) * XST + ch];
        const float4 k0 = *(const float4*)&Ks[i][0];
        const float4 k1 = *(const float4*)&Ks[i][4];
        c[0] = fmaf(k0.x, xt, c[0]); c[1] = fmaf(k0.y, xt, c[1]);
        c[2] = fmaf(k0.z, xt, c[2]); c[3] = fmaf(k0.w, xt, c[3]);
        c[4] = fmaf(k1.x, xt, c[4]); c[5] = fmaf(k1.y, xt, c[5]);
        c[6] = fmaf(k1.z, xt, c[6]); c[7] = fmaf(k1.w, xt, c[7]);
    }
    {
        float* vj = &vs[j * VST + ch * NN];
        *(float4*)(vj)     = make_float4(c[0], c[1], c[2], c[3]);
        *(float4*)(vj + 4) = make_float4(c[4], c[5], c[6], c[7]);
    }
    __syncthreads();

    // ---- phase 2: Hillis-Steele scan over 32 chunk states ----
    float s[NN];
#pragma unroll
    for (int m = 0; m < NN; ++m) s[m] = c[m];
#pragma unroll
    for (int k = 0; k < 5; ++k) {
        const int d = 1 << k;
        float prev[NN];
        if (j >= d) {
            const float* vp = &vs[(j - d) * VST + ch * NN];
            float4 p0 = *(const float4*)(vp);
            float4 p1 = *(const float4*)(vp + 4);
            prev[0] = p0.x; prev[1] = p0.y; prev[2] = p0.z; prev[3] = p0.w;
            prev[4] = p1.x; prev[5] = p1.y; prev[6] = p1.z; prev[7] = p1.w;
        }
        __syncthreads();
        if (j >= d) {
#pragma unroll
            for (int m = 0; m < NN; ++m) {
                float a = s[m];
#pragma unroll
                for (int n = 0; n < NN; ++n) a = fmaf(pw[k][m * 8 + n], prev[n], a);
                s[m] = a;
            }
            float* vj = &vs[j * VST + ch * NN];
            *(float4*)(vj)     = make_float4(s[0], s[1], s[2], s[3]);
            *(float4*)(vj + 4) = make_float4(s[4], s[5], s[6], s[7]);
        }
        __syncthreads();
    }

    // ---- phase 3: emit chunk j from true incoming state (x from LDS) ----
    float ci[NN];
    if (j > 0) {
        const float* vp = &vs[(j - 1) * VST + ch * NN];
        float4 p0 = *(const float4*)(vp);
        float4 p1 = *(const float4*)(vp + 4);
        ci[0] = p0.x; ci[1] = p0.y; ci[2] = p0.z; ci[3] = p0.w;
        ci[4] = p1.x; ci[5] = p1.y; ci[6] = p1.z; ci[7] = p1.w;
    } else {
#pragma unroll
        for (int m = 0; m < NN; ++m) ci[m] = 0.f;
    }

    float* op = out + (((size_t)b * SS + t0) * FF + f0 + ch) * NN;
#pragma unroll
    for (int i = 0; i < L; ++i) {
        const float xt = xs[(t0 + i) * XST + ch];
        float cn[NN];
#pragma unroll
        for (int m = 0; m < NN; ++m) {
            float a = Bv[m] * xt;
#pragma unroll
            for (int n = 0; n < NN; ++n) a = fmaf(As[n * NN + m], ci[n], a);
            cn[m] = a;
        }
#pragma unroll
        for (int m = 0; m < NN; ++m) ci[m] = cn[m];

        float4* o4 = (float4*)(op + (size_t)i * (FF * NN));
        o4[0] = make_float4(ci[0], ci[1], ci[2], ci[3]);
        o4[1] = make_float4(ci[4], ci[5], ci[6], ci[7]);
    }
}

extern "C" void kernel_launch(void* const* d_in, const int* in_sizes, int n_in,
                              void* d_out, int out_size, void* d_ws, size_t ws_size,
                              hipStream_t stream) {
    const float* x  = (const float*)d_in[0];
    const float* Ad = (const float*)d_in[1];
    const float* Bd = (const float*)d_in[2];
    float* out = (float*)d_out;

    const int grid = BB * (FF / CGF);   // 1024 blocks
    hipLaunchKernelGGL(hippo_fused, dim3(grid), dim3(NTF), 0, stream,
                       x, Ad, Bd, out);
}

// Round 8
// 36.233 us; speedup vs baseline: 2.6886x; 1.0238x over previous
//
#include <hip/hip_runtime.h>

#define BB 32
#define SS 512
#define FF 256
#define NN 8
#define L 16               // chunk length
#define NCH 32             // SS/L
#define CGF 8              // channels per block
#define NTF 256            // threads per block
#define XST 9              // xs row stride (words)
#define VST 68             // vs row stride (words)

__global__ __launch_bounds__(NTF) void hippo_fused2(
    const float* __restrict__ x,
    const float* __restrict__ Ad,
    const float* __restrict__ Bd,
    float* __restrict__ out)
{
    __shared__ __align__(16) float xs[SS * XST];      // 18432 B
    __shared__ __align__(16) float vs[NCH * VST];     //  8704 B
    __shared__ __align__(16) float pw[5][64];         // P^(2^k), P = M^16
    __shared__ __align__(16) float Mp[4][64];         // M^1,2,4,8
    __shared__ __align__(16) float Ks[L][NN];         // K[i] = M^(15-i) B

    const int tid = threadIdx.x;

    // XCD-chunked swizzle
    const int h  = blockIdx.x;
    const int g  = (h & 7) * 128 + (h >> 3);
    const int b  = g >> 5;
    const int f0 = (g & 31) * CGF;

    // ---- wave 0: matrix algebra  ||  waves 1-3: stage x tile ----
    if (tid < 64) {
        const int m = tid >> 3, n = tid & 7;
        Mp[0][tid] = Ad[n * NN + m];                 // M = A^T
#pragma unroll
        for (int s = 1; s < 4; ++s) {                // M^2, M^4, M^8
            float a = 0.f;
#pragma unroll
            for (int t = 0; t < 8; ++t) a = fmaf(Mp[s-1][m*8+t], Mp[s-1][t*8+n], a);
            Mp[s][tid] = a;
        }
        {   float a = 0.f;                           // M^16
#pragma unroll
            for (int t = 0; t < 8; ++t) a = fmaf(Mp[3][m*8+t], Mp[3][t*8+n], a);
            pw[0][tid] = a; }
#pragma unroll
        for (int k = 1; k < 5; ++k) {                // M^32..M^256
            float a = 0.f;
#pragma unroll
            for (int t = 0; t < 8; ++t) a = fmaf(pw[k-1][m*8+t], pw[k-1][t*8+n], a);
            pw[k][tid] = a;
        }
        if (tid < L) {                               // K[i] = M^(15-i) B
            const int e = 15 - tid;
            float v[8];
#pragma unroll
            for (int q = 0; q < 8; ++q) v[q] = Bd[q];
#pragma unroll
            for (int s = 0; s < 4; ++s) {
                if (e & (1 << s)) {
                    float nv[8];
#pragma unroll
                    for (int r = 0; r < 8; ++r) {
                        float a = 0.f;
#pragma unroll
                        for (int c2 = 0; c2 < 8; ++c2)
                            a = fmaf(Mp[s][r * 8 + c2], v[c2], a);
                        nv[r] = a;
                    }
#pragma unroll
                    for (int r = 0; r < 8; ++r) v[r] = nv[r];
                }
            }
#pragma unroll
            for (int r = 0; r < 8; ++r) Ks[tid][r] = v[r];
        }
    } else {
        const float* xb = x + (size_t)b * SS * FF + f0;
#pragma unroll
        for (int k = 0; k < 6; ++k) {
            const int i2 = (tid - 64) + k * 192;     // 0..1151, need 0..1023
            if (i2 < 1024) {
                const int t = i2 >> 1, q = i2 & 1;
                float4 v = *(const float4*)(xb + (size_t)t * FF + q * 4);
                float* d = &xs[t * XST + q * 4];
                d[0] = v.x; d[1] = v.y; d[2] = v.z; d[3] = v.w;
            }
        }
    }

    // thread-uniform A/B -> scalar regs (for emit)
    float As[NN * NN];
#pragma unroll
    for (int i = 0; i < NN * NN; ++i) As[i] = Ad[i];
    float Bv[NN];
#pragma unroll
    for (int m = 0; m < NN; ++m) Bv[m] = Bd[m];

    __syncthreads();   // barrier 1: xs + algebra ready

    // ---- phase 1: chunk-end state from zero via Krylov sum ----
    const int j  = tid >> 3;            // chunk 0..31
    const int ch = tid & 7;             // channel-in-block
    const int t0 = j * L;
    {
        float c[NN];
#pragma unroll
        for (int m = 0; m < NN; ++m) c[m] = 0.f;
#pragma unroll
        for (int i = 0; i < L; ++i) {
            const float xt = xs[(t0 + i) * XST + ch];
            const float4 k0 = *(const float4*)&Ks[i][0];
            const float4 k1 = *(const float4*)&Ks[i][4];
            c[0] = fmaf(k0.x, xt, c[0]); c[1] = fmaf(k0.y, xt, c[1]);
            c[2] = fmaf(k0.z, xt, c[2]); c[3] = fmaf(k0.w, xt, c[3]);
            c[4] = fmaf(k1.x, xt, c[4]); c[5] = fmaf(k1.y, xt, c[5]);
            c[6] = fmaf(k1.z, xt, c[6]); c[7] = fmaf(k1.w, xt, c[7]);
        }
        float* vj = &vs[j * VST + ch * NN];
        *(float4*)(vj)     = make_float4(c[0], c[1], c[2], c[3]);
        *(float4*)(vj + 4) = make_float4(c[4], c[5], c[6], c[7]);
    }
    __syncthreads();   // barrier 2: chunk-end states in vs

    // ---- phase 2: in-wave shfl Hillis-Steele (no barriers) ----
    // wave w owns channels {2w, 2w+1}; lane l -> chunk js=l>>1, ch cs=2w+(l&1)
    {
        const int lane = tid & 63;
        const int w    = tid >> 6;
        const int js   = lane >> 1;
        const int cs   = 2 * w + (lane & 1);

        float s[NN];
        {
            const float* vp = &vs[js * VST + cs * NN];
            float4 p0 = *(const float4*)(vp);
            float4 p1 = *(const float4*)(vp + 4);
            s[0] = p0.x; s[1] = p0.y; s[2] = p0.z; s[3] = p0.w;
            s[4] = p1.x; s[5] = p1.y; s[6] = p1.z; s[7] = p1.w;
        }
#pragma unroll
        for (int k = 0; k < 5; ++k) {
            const int d = 1 << k;
            float prev[NN];
#pragma unroll
            for (int m = 0; m < NN; ++m) prev[m] = __shfl_up(s[m], 2 * d, 64);
            if (js >= d) {
#pragma unroll
                for (int m = 0; m < NN; ++m) {
                    const float4 r0 = *(const float4*)&pw[k][m * 8];
                    const float4 r1 = *(const float4*)&pw[k][m * 8 + 4];
                    float a = s[m];
                    a = fmaf(r0.x, prev[0], a); a = fmaf(r0.y, prev[1], a);
                    a = fmaf(r0.z, prev[2], a); a = fmaf(r0.w, prev[3], a);
                    a = fmaf(r1.x, prev[4], a); a = fmaf(r1.y, prev[5], a);
                    a = fmaf(r1.z, prev[6], a); a = fmaf(r1.w, prev[7], a);
                    s[m] = a;
                }
            }
        }
        float* vj = &vs[js * VST + cs * NN];
        *(float4*)(vj)     = make_float4(s[0], s[1], s[2], s[3]);
        *(float4*)(vj + 4) = make_float4(s[4], s[5], s[6], s[7]);
    }
    __syncthreads();   // barrier 3: inclusive prefixes in vs

    // ---- phase 3: emit chunk j from incoming state (x from LDS) ----
    float ci[NN];
    if (j > 0) {
        const float* vp = &vs[(j - 1) * VST + ch * NN];
        float4 p0 = *(const float4*)(vp);
        float4 p1 = *(const float4*)(vp + 4);
        ci[0] = p0.x; ci[1] = p0.y; ci[2] = p0.z; ci[3] = p0.w;
        ci[4] = p1.x; ci[5] = p1.y; ci[6] = p1.z; ci[7] = p1.w;
    } else {
#pragma unroll
        for (int m = 0; m < NN; ++m) ci[m] = 0.f;
    }

    float* op = out + (((size_t)b * SS + t0) * FF + f0 + ch) * NN;
#pragma unroll
    for (int i = 0; i < L; ++i) {
        const float xt = xs[(t0 + i) * XST + ch];
        float cn[NN];
#pragma unroll
        for (int m = 0; m < NN; ++m) {
            float a = Bv[m] * xt;
#pragma unroll
            for (int n = 0; n < NN; ++n) a = fmaf(As[n * NN + m], ci[n], a);
            cn[m] = a;
        }
#pragma unroll
        for (int m = 0; m < NN; ++m) ci[m] = cn[m];

        float4* o4 = (float4*)(op + (size_t)i * (FF * NN));
        o4[0] = make_float4(ci[0], ci[1], ci[2], ci[3]);
        o4[1] = make_float4(ci[4], ci[5], ci[6], ci[7]);
    }
}

extern "C" void kernel_launch(void* const* d_in, const int* in_sizes, int n_in,
                              void* d_out, int out_size, void* d_ws, size_t ws_size,
                              hipStream_t stream) {
    const float* x  = (const float*)d_in[0];
    const float* Ad = (const float*)d_in[1];
    const float* Bd = (const float*)d_in[2];
    float* out = (float*)d_out;

    const int grid = BB * (FF / CGF);   // 1024 blocks
    hipLaunchKernelGGL(hippo_fused2, dim3(grid), dim3(NTF), 0, stream,
                       x, Ad, Bd, out);
}